// Round 3
// baseline (622.788 us; speedup 1.0000x reference)
//
#include <hip/hip_runtime.h>

#define GS 64
#define BB 128
#define NN 8192
#define KK 3
#define NXCD 8
#define BLOCKS_PER_XCD 128                 // grid = 1024
#define B_PER_XCD 16                       // 128 b / 8 XCDs
#define PTS_PER_BLOCK 64                   // 8192 / 128
#define SLICE_FLOATS (GS * GS * GS * 3)    // 786432 floats = 3 MB
#define WARM_F4_PER_BLOCK (SLICE_FLOATS / 4 / BLOCKS_PER_XCD)  // 1536

__device__ __forceinline__ float dist2(float x, float y, float z,
                                       const float* __restrict__ cpb) {
    float fx = fminf(fmaxf(floorf((x + 0.5f) * 64.0f), 0.0f), 63.0f);
    float fy = fminf(fmaxf(floorf((y + 0.5f) * 64.0f), 0.0f), 63.0f);
    float fz = fminf(fmaxf(floorf((z + 0.5f) * 64.0f), 0.0f), 63.0f);
    int ix = (int)fx, iy = (int)fy, iz = (int)fz;
    int flat = (ix * GS + iy) * GS + iz;
    const float* c = cpb + (size_t)flat * 3;
    float dx = x - c[0];
    float dy = y - c[1];
    float dz = z - c[2];
    return dx * dx + dy * dy + dz * dz;
}

__global__ void init_ws_kernel(unsigned* ws_u) {
    // zero loss accumulators (2 doubles) + per-XCD barrier counters
    ws_u[threadIdx.x] = 0u;   // first 1024 bytes
}

__global__ __launch_bounds__(256, 4) void symloss_main(
    const float* __restrict__ points, const float* __restrict__ cp,
    const float* __restrict__ plane, const float* __restrict__ quat,
    double* __restrict__ ws) {
    int raw = blockIdx.x;
    int xcd = raw & 7;          // HW: XCD = blockIdx % 8 (locality hint only)
    int w   = raw >> 3;         // local block id within XCD, 0..127

    unsigned* ctr = (unsigned*)((char*)ws + 128) + xcd * 16;  // 64B-strided

    int task = threadIdx.x >> 6;   // 0..3 (3 = warm-only helper)
    int pl   = threadIdx.x & 63;   // point-local index

    float ref_acc = 0.0f, rot_acc = 0.0f;
    float sink = 0.0f;

    for (int phase = 0; phase < B_PER_XCD; ++phase) {
        int b = xcd * B_PER_XCD + phase;
        const float* cpb = cp + (size_t)b * SLICE_FLOATS;

        // ---- warm: stream this b's 3MB slice into our XCD's L2 ----
        const float4* src = (const float4*)cpb + (size_t)w * WARM_F4_PER_BLOCK;
#pragma unroll
        for (int j = 0; j < 6; ++j) {
            float4 v = src[threadIdx.x + j * 256];
            sink += v.x + v.y + v.z + v.w;   // force full 16B load
        }

        // ---- gather: tasks 0..2 handle k = task for one point ----
        if (task < KK) {
            int k = task;
            const float* p =
                points + ((size_t)b * NN + w * PTS_PER_BLOCK + pl) * 3;
            float px = p[0], py = p[1], pz = p[2];

            // reflect
            const float* plk = plane + ((size_t)k * BB + b) * 4;
            float nx = plk[0], ny = plk[1], nz = plk[2], d = plk[3];
            float denom = nx * nx + ny * ny + nz * nz + 1e-12f;
            float t = (px * nx + py * ny + pz * nz + d) / denom;
            float rx = px - 2.0f * t * nx;
            float ry = py - 2.0f * t * ny;
            float rz = pz - 2.0f * t * nz;
            ref_acc += dist2(rx, ry, rz, cpb);

            // rotate
            const float* q = quat + ((size_t)k * BB + b) * 4;
            float qw = q[0], qx = q[1], qy = q[2], qz = q[3];
            float qn = sqrtf(qw * qw + qx * qx + qy * qy + qz * qz) + 1e-12f;
            qw /= qn; qx /= qn; qy /= qn; qz /= qn;
            float ux = qy * pz - qz * py;
            float uy = qz * px - qx * pz;
            float uz = qx * py - qy * px;
            float sx = ux + qw * px;
            float sy = uy + qw * py;
            float sz = uz + qw * pz;
            float ox = px + 2.0f * (qy * sz - qz * sy);
            float oy = py + 2.0f * (qz * sx - qx * sz);
            float oz = pz + 2.0f * (qx * sy - qy * sx);
            rot_acc += dist2(ox, oy, oz, cpb);
        }

        // ---- soft barrier (perf hint only; bounded spin, no deadlock) ----
        if (phase != B_PER_XCD - 1) {
            __syncthreads();
            if (threadIdx.x == 0) {
                unsigned target = (unsigned)((phase + 1) * BLOCKS_PER_XCD);
                __hip_atomic_fetch_add(ctr, 1u, __ATOMIC_RELEASE,
                                       __HIP_MEMORY_SCOPE_AGENT);
                int polls = 0;
                while (__hip_atomic_load(ctr, __ATOMIC_RELAXED,
                                         __HIP_MEMORY_SCOPE_AGENT) < target &&
                       polls < 1500) {
                    __builtin_amdgcn_s_sleep(1);
                    ++polls;
                }
            }
            __syncthreads();
        }
    }

    asm volatile("" ::"v"(sink));   // keep warm loads alive

    // ---- block reduction: wave shuffle (width 64) -> LDS -> atomic ----
    for (int off = 32; off > 0; off >>= 1) {
        ref_acc += __shfl_down(ref_acc, off, 64);
        rot_acc += __shfl_down(rot_acc, off, 64);
    }
    __shared__ float s_ref[4], s_rot[4];
    int wave = threadIdx.x >> 6;
    int lane = threadIdx.x & 63;
    if (lane == 0) {
        s_ref[wave] = ref_acc;
        s_rot[wave] = rot_acc;
    }
    __syncthreads();
    if (threadIdx.x == 0) {
        float r = s_ref[0] + s_ref[1] + s_ref[2] + s_ref[3];
        float o = s_rot[0] + s_rot[1] + s_rot[2] + s_rot[3];
        atomicAdd(&ws[0], (double)r);
        atomicAdd(&ws[1], (double)o);
    }
}

__global__ void finalize_kernel(const double* __restrict__ ws,
                                float* __restrict__ out) {
    if (threadIdx.x == 0) {
        const double inv = 1.0 / ((double)BB * (double)NN);
        out[0] = (float)(ws[0] * inv);
        out[1] = (float)(ws[1] * inv);
    }
}

extern "C" void kernel_launch(void* const* d_in, const int* in_sizes, int n_in,
                              void* d_out, int out_size, void* d_ws, size_t ws_size,
                              hipStream_t stream) {
    const float* points = (const float*)d_in[0];
    const float* cp     = (const float*)d_in[1];
    // d_in[2] = voxel (unused)
    const float* plane  = (const float*)d_in[3];
    const float* quat   = (const float*)d_in[4];
    float* out = (float*)d_out;
    double* ws = (double*)d_ws;

    init_ws_kernel<<<1, 256, 0, stream>>>((unsigned*)d_ws);
    symloss_main<<<NXCD * BLOCKS_PER_XCD, 256, 0, stream>>>(points, cp, plane,
                                                            quat, ws);
    finalize_kernel<<<1, 64, 0, stream>>>(ws, out);
}

// Round 4
// 312.103 us; speedup vs baseline: 1.9955x; 1.9955x over previous
//
#include <hip/hip_runtime.h>

#define GS 64
#define BB 128
#define NN 8192
#define KK 3
#define SLICE_FLOATS (GS * GS * GS * 3)   // 786432 floats = 3 MB per b
#define B_PER_XCD 16
#define BLOCKS_PER_B 192                  // 6 (k,t) streams x 32 chunks of 256 pts
#define GRID (8 * B_PER_XCD * BLOCKS_PER_B)   // 24576

__global__ void init_ws_kernel(double* ws) {
    if (threadIdx.x < 2) ws[threadIdx.x] = 0.0;
}

// One thread = one (b, k, transform, point) work item: 1 gather + ~40 VALU.
// Block-level mapping puts ONE b on ONE XCD at a time:
//   raw blockIdx round-robins XCDs (xcd = raw & 7); per-XCD sequence s walks
//   b = xcd*16 + s/192 in order, so each 3 MB cp slice is gathered by all 6
//   transform streams while L2-resident. No barriers: worst case degrades to
//   the round-2 sliding-window behavior.
__global__ __launch_bounds__(256) void symloss_main(
    const float* __restrict__ points, const float* __restrict__ cp,
    const float* __restrict__ plane, const float* __restrict__ quat,
    double* __restrict__ ws) {
    int raw = blockIdx.x;
    int xcd = raw & 7;
    int s   = raw >> 3;                 // 0..3071 per XCD
    int b   = xcd * B_PER_XCD + s / BLOCKS_PER_B;
    int j   = s % BLOCKS_PER_B;         // 0..191 within this b
    int kt  = j % 6;                    // interleave streams so all 6 advance together
    int chunk = j / 6;                  // 0..31
    int k = kt >> 1;
    int t = kt & 1;                     // 0 = reflect, 1 = rotate
    int n = chunk * 256 + threadIdx.x;

    const float* p = points + ((size_t)b * NN + n) * 3;
    float px = p[0], py = p[1], pz = p[2];
    const float* cpb = cp + (size_t)b * SLICE_FLOATS;

    float x, y, z;
    if (t == 0) {
        const float* plk = plane + ((size_t)k * BB + b) * 4;
        float nx = plk[0], ny = plk[1], nz = plk[2], d = plk[3];
        float denom = nx * nx + ny * ny + nz * nz + 1e-12f;
        float tt = (px * nx + py * ny + pz * nz + d) / denom;
        x = px - 2.0f * tt * nx;
        y = py - 2.0f * tt * ny;
        z = pz - 2.0f * tt * nz;
    } else {
        const float* q = quat + ((size_t)k * BB + b) * 4;
        float qw = q[0], qx = q[1], qy = q[2], qz = q[3];
        float qn = sqrtf(qw * qw + qx * qx + qy * qy + qz * qz) + 1e-12f;
        qw /= qn; qx /= qn; qy /= qn; qz /= qn;
        float ux = qy * pz - qz * py;
        float uy = qz * px - qx * pz;
        float uz = qx * py - qy * px;
        float sx = ux + qw * px;
        float sy = uy + qw * py;
        float sz = uz + qw * pz;
        x = px + 2.0f * (qy * sz - qz * sy);
        y = py + 2.0f * (qz * sx - qx * sz);
        z = pz + 2.0f * (qx * sy - qy * sx);
    }

    // voxel gather + squared distance
    float fx = fminf(fmaxf(floorf((x + 0.5f) * 64.0f), 0.0f), 63.0f);
    float fy = fminf(fmaxf(floorf((y + 0.5f) * 64.0f), 0.0f), 63.0f);
    float fz = fminf(fmaxf(floorf((z + 0.5f) * 64.0f), 0.0f), 63.0f);
    int flat = (((int)fx * GS) + (int)fy) * GS + (int)fz;
    const float* c = cpb + (size_t)flat * 3;
    float dx = x - c[0];
    float dy = y - c[1];
    float dz = z - c[2];
    float acc = dx * dx + dy * dy + dz * dz;

    // block reduction: wave shuffle (width 64) -> LDS -> one atomic per block
    for (int off = 32; off > 0; off >>= 1)
        acc += __shfl_down(acc, off, 64);
    __shared__ float sbuf[4];
    int wave = threadIdx.x >> 6;
    int lane = threadIdx.x & 63;
    if (lane == 0) sbuf[wave] = acc;
    __syncthreads();
    if (threadIdx.x == 0) {
        float v = sbuf[0] + sbuf[1] + sbuf[2] + sbuf[3];
        atomicAdd(&ws[t], (double)v);   // t uniform per block
    }
}

__global__ void finalize_kernel(const double* __restrict__ ws,
                                float* __restrict__ out) {
    if (threadIdx.x == 0) {
        const double inv = 1.0 / ((double)BB * (double)NN);
        out[0] = (float)(ws[0] * inv);
        out[1] = (float)(ws[1] * inv);
    }
}

extern "C" void kernel_launch(void* const* d_in, const int* in_sizes, int n_in,
                              void* d_out, int out_size, void* d_ws, size_t ws_size,
                              hipStream_t stream) {
    const float* points = (const float*)d_in[0];
    const float* cp     = (const float*)d_in[1];
    // d_in[2] = voxel (unused)
    const float* plane  = (const float*)d_in[3];
    const float* quat   = (const float*)d_in[4];
    float* out = (float*)d_out;
    double* ws = (double*)d_ws;

    init_ws_kernel<<<1, 64, 0, stream>>>(ws);
    symloss_main<<<GRID, 256, 0, stream>>>(points, cp, plane, quat, ws);
    finalize_kernel<<<1, 64, 0, stream>>>(ws, out);
}

// Round 5
// 65.292 us; speedup vs baseline: 9.5386x; 4.7801x over previous
//
#include <hip/hip_runtime.h>

#define GS 64
#define BB 128
#define NN 8192
#define KK 3
#define SLICE_FLOATS (GS * GS * GS * 3)   // 786432 floats = 3 MB per b
#define B_PER_XCD 16
#define BLOCKS_PER_B 96                   // 3 k-streams x 32 chunks of 256 pts
#define GRID (BB * BLOCKS_PER_B)          // 12288
#define SEQ_PER_XCD (GRID / 8)            // 1536

// One thread = one (b, k, point): reflect+rotate => 2 independent gathers.
// Per-XCD block ordering walks b's sequentially (xcd = blockIdx & 7 round-robin),
// keeping ~2-3 cp slices (~8 MB) in flight per XCD => L2/L3-resident gathers.
// NO contended atomics: each block stores a float2 partial to its own slot.
__global__ __launch_bounds__(256) void symloss_main(
    const float* __restrict__ points, const float* __restrict__ cp,
    const float* __restrict__ plane, const float* __restrict__ quat,
    float2* __restrict__ partials) {
    int raw = blockIdx.x;
    int xcd = raw & 7;
    int s   = raw >> 3;                   // 0..1535 per XCD
    int b   = xcd * B_PER_XCD + s / BLOCKS_PER_B;
    int j   = s % BLOCKS_PER_B;           // 0..95
    int k   = j % 3;                      // interleave k-streams in time
    int chunk = j / 3;                    // 0..31
    int n = chunk * 256 + threadIdx.x;

    const float* p = points + ((size_t)b * NN + n) * 3;
    float px = p[0], py = p[1], pz = p[2];
    const float* cpb = cp + (size_t)b * SLICE_FLOATS;

    // ---- reflect (b,k uniform per block -> scalar plane/quat loads) ----
    const float* plk = plane + ((size_t)k * BB + b) * 4;
    float nx = plk[0], ny = plk[1], nz = plk[2], d = plk[3];
    float denom = nx * nx + ny * ny + nz * nz + 1e-12f;
    float tt = (px * nx + py * ny + pz * nz + d) / denom;
    float rx = px - 2.0f * tt * nx;
    float ry = py - 2.0f * tt * ny;
    float rz = pz - 2.0f * tt * nz;

    // ---- rotate ----
    const float* q = quat + ((size_t)k * BB + b) * 4;
    float qw = q[0], qx = q[1], qy = q[2], qz = q[3];
    float qn = sqrtf(qw * qw + qx * qx + qy * qy + qz * qz) + 1e-12f;
    qw /= qn; qx /= qn; qy /= qn; qz /= qn;
    float ux = qy * pz - qz * py;
    float uy = qz * px - qx * pz;
    float uz = qx * py - qy * px;
    float sx = ux + qw * px;
    float sy = uy + qw * py;
    float sz = uz + qw * pz;
    float ox = px + 2.0f * (qy * sz - qz * sy);
    float oy = py + 2.0f * (qz * sx - qx * sz);
    float oz = pz + 2.0f * (qx * sy - qy * sx);

    // ---- two independent gathers (issue both, then compute) ----
    float fx = fminf(fmaxf(floorf((rx + 0.5f) * 64.0f), 0.0f), 63.0f);
    float fy = fminf(fmaxf(floorf((ry + 0.5f) * 64.0f), 0.0f), 63.0f);
    float fz = fminf(fmaxf(floorf((rz + 0.5f) * 64.0f), 0.0f), 63.0f);
    int flat_r = (((int)fx * GS) + (int)fy) * GS + (int)fz;
    float gx = fminf(fmaxf(floorf((ox + 0.5f) * 64.0f), 0.0f), 63.0f);
    float gy = fminf(fmaxf(floorf((oy + 0.5f) * 64.0f), 0.0f), 63.0f);
    float gz = fminf(fmaxf(floorf((oz + 0.5f) * 64.0f), 0.0f), 63.0f);
    int flat_o = (((int)gx * GS) + (int)gy) * GS + (int)gz;

    const float* cr = cpb + (size_t)flat_r * 3;
    const float* co = cpb + (size_t)flat_o * 3;
    float c0 = cr[0], c1 = cr[1], c2 = cr[2];
    float e0 = co[0], e1 = co[1], e2 = co[2];

    float drx = rx - c0, dry = ry - c1, drz = rz - c2;
    float dox = ox - e0, doy = oy - e1, doz = oz - e2;
    float ref_acc = drx * drx + dry * dry + drz * drz;
    float rot_acc = dox * dox + doy * doy + doz * doz;

    // ---- block reduction: shuffle (width 64) -> LDS -> one plain store ----
    for (int off = 32; off > 0; off >>= 1) {
        ref_acc += __shfl_down(ref_acc, off, 64);
        rot_acc += __shfl_down(rot_acc, off, 64);
    }
    __shared__ float s_ref[4], s_rot[4];
    int wave = threadIdx.x >> 6;
    int lane = threadIdx.x & 63;
    if (lane == 0) {
        s_ref[wave] = ref_acc;
        s_rot[wave] = rot_acc;
    }
    __syncthreads();
    if (threadIdx.x == 0) {
        float2 v;
        v.x = s_ref[0] + s_ref[1] + s_ref[2] + s_ref[3];
        v.y = s_rot[0] + s_rot[1] + s_rot[2] + s_rot[3];
        partials[blockIdx.x] = v;   // distinct slot per block, no atomics
    }
}

__global__ __launch_bounds__(1024) void finalize_kernel(
    const float2* __restrict__ partials, float* __restrict__ out) {
    double r = 0.0, o = 0.0;
    for (int i = threadIdx.x; i < GRID; i += 1024) {
        float2 v = partials[i];
        r += (double)v.x;
        o += (double)v.y;
    }
    __shared__ double s_r[1024], s_o[1024];
    s_r[threadIdx.x] = r;
    s_o[threadIdx.x] = o;
    __syncthreads();
    for (int off = 512; off > 0; off >>= 1) {
        if (threadIdx.x < off) {
            s_r[threadIdx.x] += s_r[threadIdx.x + off];
            s_o[threadIdx.x] += s_o[threadIdx.x + off];
        }
        __syncthreads();
    }
    if (threadIdx.x == 0) {
        const double inv = 1.0 / ((double)BB * (double)NN);
        out[0] = (float)(s_r[0] * inv);
        out[1] = (float)(s_o[0] * inv);
    }
}

extern "C" void kernel_launch(void* const* d_in, const int* in_sizes, int n_in,
                              void* d_out, int out_size, void* d_ws, size_t ws_size,
                              hipStream_t stream) {
    const float* points = (const float*)d_in[0];
    const float* cp     = (const float*)d_in[1];
    // d_in[2] = voxel (unused)
    const float* plane  = (const float*)d_in[3];
    const float* quat   = (const float*)d_in[4];
    float* out = (float*)d_out;
    float2* partials = (float2*)d_ws;     // 12288 * 8 B = 96 KB

    symloss_main<<<GRID, 256, 0, stream>>>(points, cp, plane, quat, partials);
    finalize_kernel<<<1, 1024, 0, stream>>>(partials, out);
}

// Round 6
// 62.297 us; speedup vs baseline: 9.9971x; 1.0481x over previous
//
#include <hip/hip_runtime.h>

#define GS 64
#define BB 128
#define NN 8192
#define KK 3
#define SLICE_FLOATS (GS * GS * GS * 3)   // 786432 floats = 3 MB per b
#define B_PER_XCD 16
#define BLOCKS_PER_B 32                   // 32 chunks of 256 pts; all k per thread
#define GRID (BB * BLOCKS_PER_B)          // 4096

// One thread = one (b, point): all 3 k's, reflect+rotate => 6 independent
// gathers issued back-to-back (deep MLP), points read once.
// Per-XCD block ordering walks b's sequentially (xcd = blockIdx & 7
// round-robin), keeping ~1-2 cp slices (~3-6 MB) live per XCD => L2-resident
// gathers. No contended atomics: per-block float2 partial to a distinct slot.
__global__ __launch_bounds__(256) void symloss_main(
    const float* __restrict__ points, const float* __restrict__ cp,
    const float* __restrict__ plane, const float* __restrict__ quat,
    float2* __restrict__ partials) {
    int raw = blockIdx.x;
    int xcd = raw & 7;
    int s   = raw >> 3;                   // 0..511 per XCD
    int b   = xcd * B_PER_XCD + s / BLOCKS_PER_B;
    int chunk = s % BLOCKS_PER_B;         // 0..31
    int n = chunk * 256 + threadIdx.x;

    const float* p = points + ((size_t)b * NN + n) * 3;
    float px = p[0], py = p[1], pz = p[2];
    const float* cpb = cp + (size_t)b * SLICE_FLOATS;

    // transformed coords for all 6 streams
    float tx[2 * KK], ty[2 * KK], tz[2 * KK];

#pragma unroll
    for (int k = 0; k < KK; ++k) {
        // ---- reflect (b,k uniform per block -> scalar loads) ----
        const float* plk = plane + ((size_t)k * BB + b) * 4;
        float nx = plk[0], ny = plk[1], nz = plk[2], d = plk[3];
        float denom = nx * nx + ny * ny + nz * nz + 1e-12f;
        float tt = (px * nx + py * ny + pz * nz + d) / denom;
        tx[k] = px - 2.0f * tt * nx;
        ty[k] = py - 2.0f * tt * ny;
        tz[k] = pz - 2.0f * tt * nz;

        // ---- rotate ----
        const float* q = quat + ((size_t)k * BB + b) * 4;
        float qw = q[0], qx = q[1], qy = q[2], qz = q[3];
        float qn = sqrtf(qw * qw + qx * qx + qy * qy + qz * qz) + 1e-12f;
        qw /= qn; qx /= qn; qy /= qn; qz /= qn;
        float ux = qy * pz - qz * py;
        float uy = qz * px - qx * pz;
        float uz = qx * py - qy * px;
        float sx = ux + qw * px;
        float sy = uy + qw * py;
        float sz = uz + qw * pz;
        tx[KK + k] = px + 2.0f * (qy * sz - qz * sy);
        ty[KK + k] = py + 2.0f * (qz * sx - qx * sz);
        tz[KK + k] = pz + 2.0f * (qx * sy - qy * sx);
    }

    // ---- compute all 6 cell addresses, then issue all 6 gathers ----
    const float* cptr[2 * KK];
#pragma unroll
    for (int i = 0; i < 2 * KK; ++i) {
        float fx = fminf(fmaxf(floorf((tx[i] + 0.5f) * 64.0f), 0.0f), 63.0f);
        float fy = fminf(fmaxf(floorf((ty[i] + 0.5f) * 64.0f), 0.0f), 63.0f);
        float fz = fminf(fmaxf(floorf((tz[i] + 0.5f) * 64.0f), 0.0f), 63.0f);
        int flat = (((int)fx * GS) + (int)fy) * GS + (int)fz;
        cptr[i] = cpb + (size_t)flat * 3;
    }
    float cx[2 * KK], cy[2 * KK], cz[2 * KK];
#pragma unroll
    for (int i = 0; i < 2 * KK; ++i) {
        cx[i] = cptr[i][0];
        cy[i] = cptr[i][1];
        cz[i] = cptr[i][2];
    }

    float ref_acc = 0.0f, rot_acc = 0.0f;
#pragma unroll
    for (int i = 0; i < KK; ++i) {
        float dx = tx[i] - cx[i], dy = ty[i] - cy[i], dz = tz[i] - cz[i];
        ref_acc += dx * dx + dy * dy + dz * dz;
    }
#pragma unroll
    for (int i = KK; i < 2 * KK; ++i) {
        float dx = tx[i] - cx[i], dy = ty[i] - cy[i], dz = tz[i] - cz[i];
        rot_acc += dx * dx + dy * dy + dz * dz;
    }

    // ---- block reduction: shuffle (width 64) -> LDS -> one plain store ----
    for (int off = 32; off > 0; off >>= 1) {
        ref_acc += __shfl_down(ref_acc, off, 64);
        rot_acc += __shfl_down(rot_acc, off, 64);
    }
    __shared__ float s_ref[4], s_rot[4];
    int wave = threadIdx.x >> 6;
    int lane = threadIdx.x & 63;
    if (lane == 0) {
        s_ref[wave] = ref_acc;
        s_rot[wave] = rot_acc;
    }
    __syncthreads();
    if (threadIdx.x == 0) {
        float2 v;
        v.x = s_ref[0] + s_ref[1] + s_ref[2] + s_ref[3];
        v.y = s_rot[0] + s_rot[1] + s_rot[2] + s_rot[3];
        partials[blockIdx.x] = v;   // distinct slot per block, no atomics
    }
}

__global__ __launch_bounds__(1024) void finalize_kernel(
    const float2* __restrict__ partials, float* __restrict__ out) {
    double r = 0.0, o = 0.0;
    for (int i = threadIdx.x; i < GRID; i += 1024) {
        float2 v = partials[i];
        r += (double)v.x;
        o += (double)v.y;
    }
    __shared__ double s_r[1024], s_o[1024];
    s_r[threadIdx.x] = r;
    s_o[threadIdx.x] = o;
    __syncthreads();
    for (int off = 512; off > 0; off >>= 1) {
        if (threadIdx.x < off) {
            s_r[threadIdx.x] += s_r[threadIdx.x + off];
            s_o[threadIdx.x] += s_o[threadIdx.x + off];
        }
        __syncthreads();
    }
    if (threadIdx.x == 0) {
        const double inv = 1.0 / ((double)BB * (double)NN);
        out[0] = (float)(s_r[0] * inv);
        out[1] = (float)(s_o[0] * inv);
    }
}

extern "C" void kernel_launch(void* const* d_in, const int* in_sizes, int n_in,
                              void* d_out, int out_size, void* d_ws, size_t ws_size,
                              hipStream_t stream) {
    const float* points = (const float*)d_in[0];
    const float* cp     = (const float*)d_in[1];
    // d_in[2] = voxel (unused)
    const float* plane  = (const float*)d_in[3];
    const float* quat   = (const float*)d_in[4];
    float* out = (float*)d_out;
    float2* partials = (float2*)d_ws;     // 4096 * 8 B = 32 KB

    symloss_main<<<GRID, 256, 0, stream>>>(points, cp, plane, quat, partials);
    finalize_kernel<<<1, 1024, 0, stream>>>(partials, out);
}